// Round 6
// baseline (404.316 us; speedup 1.0000x reference)
//
#include <hip/hip_runtime.h>
#include <math.h>

// Problem constants (reference: B=8, C=32, O=32, H=256, W=256, K=5, pad=2)
constexpr int IMG_H = 256;
constexpr int IMG_W = 256;
constexpr int NB = 8;
constexpr int NC = 32;
constexpr int NO = 32;
constexpr int PLANE = IMG_H * IMG_W;          // 65536
constexpr int HALF = NB * NC * PLANE;         // 16,777,216 floats (64 MB)

// Fused kernel tiling: block = one (b, 32x8 spatial tile), thread = one pixel.
// Channels streamed 2-at-a-time through 4 LDS buffers (2 pairs, pair-alternate)
// with ONE barrier per channel-pair (16 barriers/block).
constexpr int TW = 32;                        // tile width
constexpr int TH = 8;                         // tile height
constexpr int NT = TW * TH;                   // 256 threads
constexpr int RR = TH + 4;                    // 12 region rows
constexpr int RC = 40;                        // stored cols [w0-4, w0+36)
constexpr int RSB = RC * 4;                   // 160 B row stride
constexpr int PXB = RR * RSB;                 // 1920 B per array (P or V)
constexpr int BUFB = 2 * PXB;                 // 3840 B per channel buffer
constexpr int NTASK = RR * 20;                // 240 f2 staging tasks per channel
constexpr int TILES = (IMG_W / TW) * (IMG_H / TH);  // 256 tiles per image
constexpr int NBLK = TILES * NB;              // 2048 blocks = 8/CU issued

#define EPSV 1e-20f

typedef float f4 __attribute__((ext_vector_type(4)));
typedef float f2 __attribute__((ext_vector_type(2)));

__device__ __forceinline__ float rcpf_(float x) { return __builtin_amdgcn_rcpf(x); }
__device__ __forceinline__ float softplusf_(float x) {
  return fmaxf(x, 0.0f) + log1pf(expf(-fabsf(x)));
}

// ws layout (floats): [0..31] wp, [32..831] sw (c-major, 25/ch),
// [832..1855] cwT[c][o] (transposed), [1856] sum(sw), [1857] sum(cw)
__global__ void weights_kernel(const float* __restrict__ wp_raw,
                               const float* __restrict__ sw_raw,
                               const float* __restrict__ cw_raw,
                               float* __restrict__ ws) {
  __shared__ float red[256];
  const int t = threadIdx.x;
  if (t < 32) ws[t] = softplusf_(wp_raw[t]);
  float ssum = 0.f;
  for (int i = t; i < NC * 25; i += 256) {
    float v = softplusf_(sw_raw[i]);
    ws[32 + i] = v;
    ssum += v;
  }
  float csum = 0.f;
  for (int i = t; i < NO * NC; i += 256) {
    float v = softplusf_(cw_raw[i]);
    int o = i >> 5, c = i & 31;
    ws[832 + c * NO + o] = v;  // transposed: [c][o]
    csum += v;
  }
  red[t] = ssum; __syncthreads();
  for (int off = 128; off; off >>= 1) { if (t < off) red[t] += red[t + off]; __syncthreads(); }
  const float S_sw = red[0];
  __syncthreads();
  red[t] = csum; __syncthreads();
  for (int off = 128; off; off >>= 1) { if (t < off) red[t] += red[t + off]; __syncthreads(); }
  if (t == 0) { ws[1856] = S_sw; ws[1857] = red[0]; }
}

// Pointwise gradient-propagation math. Requires cdv/cgv pre-zeroed for
// OOB pixels (then Pv = Vv = 0 follows algebraically, no NaN).
__device__ __forceinline__ void pointwise_pv(
    float dv, float cdv, float gxv, float cgv, int gw,
    float wpc, float inv_wp1, float& Pv, float& Vv) {
  // d_left = d with last col zeroed; d_right = d with first col zeroed
  float dl  = (gw == IMG_W - 1) ? 0.f : dv;
  float cdl = (gw == IMG_W - 1) ? 0.f : cdv;
  float dr  = (gw == 0) ? 0.f : dv;
  float cdr = (gw == 0) ? 0.f : cdv;
  float cfd = cdl * cdr;                                      // cgx_from_ds
  float height = (cdl * dl + cdr * dr) * rcpf_(cdl + cdr + EPSV);
  float gfd = (dr - dl) * 0.5f * rcpf_(height + EPSV);        // gx_from_ds
  float den = fmaf(wpc, cgv, cfd);                            // wp*cgx + cgx_from_ds
  float num = fmaf(wpc * cgv, gxv, cfd * gfd);
  float gprop = num * rcpf_(den + EPSV);
  float cprop = den * inv_wp1;
  Pv = cprop;
  Vv = cprop * gprop;
}

// Per-thread staging-task geometry (loop-invariant, precomputed once).
struct TaskGeo {
  int goff;   // within-plane element offset of the f2 load (clamped, even)
  int gc0;    // true global col of element 0 (may be OOB; for edge tests)
  float m0, m1;  // in-bounds masks for the 2 elements
  int wb;     // LDS byte offset within a P-region
};

__device__ __forceinline__ TaskGeo make_geo(int task, int h0, int w0) {
  TaskGeo G;
  const int R = task / 20;
  const int hq = task - R * 20;
  const int gh = h0 + R - 2;
  const int ghc = min(max(gh, 0), IMG_H - 1);
  const int g0 = w0 - 4 + 2 * hq;
  const int g0c = min(max(g0, 0), IMG_W - 2);     // even => 8B aligned
  G.goff = ghc * IMG_W + g0c;
  G.gc0 = g0;
  const bool rowv = (unsigned)gh < (unsigned)IMG_H;
  G.m0 = (rowv & ((unsigned)g0 < (unsigned)IMG_W)) ? 1.f : 0.f;
  G.m1 = (rowv & ((unsigned)(g0 + 1) < (unsigned)IMG_W)) ? 1.f : 0.f;
  G.wb = R * RSB + hq * 8;
  return G;
}

__device__ __forceinline__ void stage_pv(f2 vd, f2 vc, f2 vg, f2 vx,
                                         const TaskGeo& G, float wpc,
                                         float inv_wp1, char* dst) {
  float P0, V0, P1, V1;
  pointwise_pv(vd[0], vc[0] * G.m0, vg[0], vx[0] * G.m0, G.gc0,
               wpc, inv_wp1, P0, V0);
  pointwise_pv(vd[1], vc[1] * G.m1, vg[1], vx[1] * G.m1, G.gc0 + 1,
               wpc, inv_wp1, P1, V1);
  f2 Pw; Pw[0] = P0; Pw[1] = P1;
  f2 Vw; Vw[0] = V0; Vw[1] = V1;
  *(f2*)(dst + G.wb) = Pw;
  *(f2*)(dst + PXB + G.wb) = Vw;
}

// ---------------------------------------------------------------------------
// Fully fused kernel: pointwise prop + depthwise 5x5 + 1x1 channel conv.
//
// R5 measured the single-channel-per-barrier version at 167us with all pipes
// <45% (VALU 70us, LDS ~50us, HBM ~48us of a 167us kernel): phase-serialized.
// This version targets overlap:
//   - 2 channels per barrier phase (16 barriers; 4 LDS buffers, pair-
//     alternating; hazard proof: iter i+2's writes to pair q are preceded in
//     every thread by iter i+1's barrier, which is preceded by iter i's conv
//     reads of pair q).
//   - staging work 480 f2-tasks over 256 threads (uniform; round-0 task for
//     all threads, round-1 for t<224).
//   - 256-thread blocks, 2048 blocks = 8/CU issued vs ~4 resident -> backfill
//     smooths barrier stalls and tail (R5 had exactly-4/CU, no spare, occ 38%).
//   - prefetch: next pair's 8 f2 global loads issued before this pair's conv.
// LDS 15,360 B. Accumulators 64 VGPR statically indexed.
// ---------------------------------------------------------------------------
__global__ __launch_bounds__(NT, 4) void fused_kernel(
    const float* __restrict__ dp, const float* __restrict__ cdp,
    const float* __restrict__ gxp, const float* __restrict__ cgxp,
    const float* __restrict__ ws, const float* __restrict__ bias,
    float* __restrict__ out) {
  __shared__ __align__(16) char shb[4 * BUFB];  // 15,360 B

  const int t = threadIdx.x;

  // XCD-aware swizzle: 2048 blocks, image k -> XCD k (assuming round-robin
  // wg->XCD; if mapping differs this is a harmless permutation).
  const int wg = blockIdx.x;
  const int virt = (wg & 7) * TILES + (wg >> 3);
  const int b = virt >> 8;                       // /256 tiles
  const int tile = virt & (TILES - 1);
  const int tx = tile & 7, ty = tile >> 3;       // 8 x 32 tile grid
  const int w0 = tx * TW, h0 = ty * TH;

  const float Ssw = ws[1856], Scw = ws[1857];
  const float epsS = EPSV * Ssw;
  const float oscale = rcpf_(Ssw) * rcpf_(Scw);

  // ---- staging task assignment (2 channels x 240 tasks = 480 over 256) ----
  // round 0: all threads. t<240 -> (ch g+0, task t); t>=240 -> (ch g+1, t-240)
  // round 1: t<224 -> (ch g+1, task t+16)
  const int f0 = (t >= NTASK) ? 1 : 0;
  const TaskGeo G0 = make_geo(t - NTASK * f0, h0, w0);
  const bool act1 = (t < 2 * NTASK - NT);        // t < 224
  const TaskGeo G1 = make_geo(min(t + (NT - NTASK), NTASK - 1), h0, w0);

  // ---- conv geometry ----
  const int x = t & (TW - 1);
  const int r = t >> 5;                          // 0..7
  const int cvb = r * RSB + (x + 2) * 4;         // window base byte
  const int pixoff = (h0 + r) * IMG_W + (w0 + x);

  const int planebase = b * NC * PLANE;

  float accN[32], accD[32];
  #pragma unroll
  for (int o = 0; o < 32; ++o) { accN[o] = 0.f; accD[o] = 0.f; }

  // prologue: prefetch channel pair {0,1}
  f2 d0, c0, g0v, x0, d1, c1, g1v, x1;
  {
    const int p0 = planebase + (0 + f0) * PLANE + G0.goff;
    d0 = *(const f2*)(dp + p0);  c0 = *(const f2*)(cdp + p0);
    g0v = *(const f2*)(gxp + p0); x0 = *(const f2*)(cgxp + p0);
    if (act1) {
      const int p1 = planebase + 1 * PLANE + G1.goff;
      d1 = *(const f2*)(dp + p1);  c1 = *(const f2*)(cdp + p1);
      g1v = *(const f2*)(gxp + p1); x1 = *(const f2*)(cgxp + p1);
    }
  }

  #pragma unroll 1
  for (int g = 0; g < NC; g += 2) {
    const int q = (g >> 1) & 1;                  // buffer pair
    char* bufA = shb + (2 * q) * BUFB;           // channel g
    char* bufB = shb + (2 * q + 1) * BUFB;       // channel g+1

    // channel weights (wave-uniform scalar loads) + per-lane select for f0
    const float wpA = ws[g], wpB = ws[g + 1];
    const float invA = rcpf_(wpA + 1.0f), invB = rcpf_(wpB + 1.0f);
    const float wp0 = f0 ? wpB : wpA;
    const float inv0 = f0 ? invB : invA;

    // stage both channels of this pair
    stage_pv(d0, c0, g0v, x0, G0, wp0, inv0, f0 ? bufB : bufA);
    if (act1) stage_pv(d1, c1, g1v, x1, G1, wpB, invB, bufB);

    // prefetch next pair (latency hidden under this pair's conv)
    if (g + 2 < NC) {
      const int p0 = planebase + (g + 2 + f0) * PLANE + G0.goff;
      d0 = *(const f2*)(dp + p0);  c0 = *(const f2*)(cdp + p0);
      g0v = *(const f2*)(gxp + p0); x0 = *(const f2*)(cgxp + p0);
      if (act1) {
        const int p1 = planebase + (g + 3) * PLANE + G1.goff;
        d1 = *(const f2*)(dp + p1);  c1 = *(const f2*)(cdp + p1);
        g1v = *(const f2*)(gxp + p1); x1 = *(const f2*)(cgxp + p1);
      }
    }

    __syncthreads();  // pair q (P,V for ch g, g+1) complete

    // depthwise 5x5 for both channels at this thread's pixel
    const char* bpA = bufA + cvb;
    const char* bpB = bufB + cvb;
    const float* swA = ws + 32 + g * 25;
    const float* swB = swA + 25;
    float DA = 0.f, NA = 0.f, DB = 0.f, NBv = 0.f;
    #pragma unroll
    for (int kr = 0; kr < 5; ++kr) {
      #pragma unroll
      for (int kc = 0; kc < 5; ++kc) {
        const int off = kr * RSB + kc * 4;
        const float wA = swA[kr * 5 + kc];
        const float wB = swB[kr * 5 + kc];
        DA  = fmaf(wA, *(const float*)(bpA + off), DA);
        NA  = fmaf(wA, *(const float*)(bpA + PXB + off), NA);
        DB  = fmaf(wB, *(const float*)(bpB + off), DB);
        NBv = fmaf(wB, *(const float*)(bpB + PXB + off), NBv);
      }
    }

    // rank-2 update of the 1x1-conv accumulators
    const float* cwA = ws + 832 + g * NO;
    const float* cwB = cwA + NO;
    #pragma unroll
    for (int o = 0; o < 32; ++o) {
      accD[o] = fmaf(cwB[o], DB, fmaf(cwA[o], DA, accD[o]));
      accN[o] = fmaf(cwB[o], NBv, fmaf(cwA[o], NA, accN[o]));
    }
    // next iteration writes the OTHER buffer pair; writes to THIS pair occur
    // two iterations later, fenced by the next iteration's barrier.
  }

  // epilogue: folded normalization + store
  //   gx[o]  = accN[o]/(accD[o] + EPS*Ssw) + bias[o]
  //   cgx[o] = accD[o]/(Ssw*Scw)
  const int ob = b * NO * PLANE + pixoff;
  #pragma unroll
  for (int o = 0; o < 32; ++o) {
    const float g = fmaf(accN[o], rcpf_(accD[o] + epsS), bias[o]);
    const float cg = accD[o] * oscale;
    out[ob + o * PLANE] = g;
    out[HALF + ob + o * PLANE] = cg;
  }
}

extern "C" void kernel_launch(void* const* d_in, const int* in_sizes, int n_in,
                              void* d_out, int out_size, void* d_ws, size_t ws_size,
                              hipStream_t stream) {
  const float* dp   = (const float*)d_in[0];
  const float* cdp  = (const float*)d_in[1];
  const float* gxp  = (const float*)d_in[2];
  const float* cgxp = (const float*)d_in[3];
  const float* wp   = (const float*)d_in[4];
  const float* sw   = (const float*)d_in[5];
  const float* cw   = (const float*)d_in[6];
  const float* bias = (const float*)d_in[7];
  float* out = (float*)d_out;
  float* ws  = (float*)d_ws;

  weights_kernel<<<1, 256, 0, stream>>>(wp, sw, cw, ws);
  fused_kernel<<<NBLK, NT, 0, stream>>>(dp, cdp, gxp, cgxp, ws, bias, out);
}

// Round 7
// 397.304 us; speedup vs baseline: 1.0176x; 1.0176x over previous
//
#include <hip/hip_runtime.h>
#include <math.h>

// Problem constants (reference: B=8, C=32, O=32, H=256, W=256, K=5, pad=2)
constexpr int IMG_H = 256;
constexpr int IMG_W = 256;
constexpr int NB = 8;
constexpr int NC = 32;
constexpr int NO = 32;
constexpr int PLANE = IMG_H * IMG_W;          // 65536
constexpr int HALF = NB * NC * PLANE;         // 16,777,216 floats (64 MB)

// Fused kernel tiling (R5-proven geometry): block = one (b, 16x32 tile),
// thread = one pixel. Channels streamed 2 per barrier phase through 4 LDS
// buffers. P,V interleaved as f2 per pixel (halves LDS instruction count).
constexpr int TW = 16;                        // tile width
constexpr int TH = 32;                        // tile height
constexpr int NT = TW * TH;                   // 512 threads
constexpr int RR = TH + 4;                    // 36 region rows
constexpr int RC = 24;                        // stored cols [w0-4, w0+20)
constexpr int RSB = RC * 8;                   // 192 B row stride (f2/px)
constexpr int BUFB = RR * RSB;                // 6912 B per channel buffer
constexpr int NTASK = RR * 12;                // 432 f2-pair staging tasks/ch
constexpr int TILES = (IMG_W / TW) * (IMG_H / TH);  // 128 tiles per image

#define EPSV 1e-20f

typedef float f4 __attribute__((ext_vector_type(4)));
typedef float f2 __attribute__((ext_vector_type(2)));

__device__ __forceinline__ float rcpf_(float x) { return __builtin_amdgcn_rcpf(x); }
__device__ __forceinline__ float softplusf_(float x) {
  return fmaxf(x, 0.0f) + log1pf(expf(-fabsf(x)));
}

// ws layout (floats): [0..31] wp, [32..831] sw (c-major, 25/ch),
// [832..1855] cwT[c][o] (transposed), [1856] sum(sw), [1857] sum(cw)
__global__ void weights_kernel(const float* __restrict__ wp_raw,
                               const float* __restrict__ sw_raw,
                               const float* __restrict__ cw_raw,
                               float* __restrict__ ws) {
  __shared__ float red[256];
  const int t = threadIdx.x;
  if (t < 32) ws[t] = softplusf_(wp_raw[t]);
  float ssum = 0.f;
  for (int i = t; i < NC * 25; i += 256) {
    float v = softplusf_(sw_raw[i]);
    ws[32 + i] = v;
    ssum += v;
  }
  float csum = 0.f;
  for (int i = t; i < NO * NC; i += 256) {
    float v = softplusf_(cw_raw[i]);
    int o = i >> 5, c = i & 31;
    ws[832 + c * NO + o] = v;  // transposed: [c][o]
    csum += v;
  }
  red[t] = ssum; __syncthreads();
  for (int off = 128; off; off >>= 1) { if (t < off) red[t] += red[t + off]; __syncthreads(); }
  const float S_sw = red[0];
  __syncthreads();
  red[t] = csum; __syncthreads();
  for (int off = 128; off; off >>= 1) { if (t < off) red[t] += red[t + off]; __syncthreads(); }
  if (t == 0) { ws[1856] = S_sw; ws[1857] = red[0]; }
}

// Pointwise gradient-propagation math. Requires cdv/cgv pre-zeroed for
// OOB pixels (then Pv = Vv = 0 follows algebraically, no NaN).
__device__ __forceinline__ void pointwise_pv(
    float dv, float cdv, float gxv, float cgv, int gw,
    float wpc, float inv_wp1, float& Pv, float& Vv) {
  // d_left = d with last col zeroed; d_right = d with first col zeroed
  float dl  = (gw == IMG_W - 1) ? 0.f : dv;
  float cdl = (gw == IMG_W - 1) ? 0.f : cdv;
  float dr  = (gw == 0) ? 0.f : dv;
  float cdr = (gw == 0) ? 0.f : cdv;
  float cfd = cdl * cdr;                                      // cgx_from_ds
  float height = (cdl * dl + cdr * dr) * rcpf_(cdl + cdr + EPSV);
  float gfd = (dr - dl) * 0.5f * rcpf_(height + EPSV);        // gx_from_ds
  float den = fmaf(wpc, cgv, cfd);                            // wp*cgx + cgx_from_ds
  float num = fmaf(wpc * cgv, gxv, cfd * gfd);
  float gprop = num * rcpf_(den + EPSV);
  float cprop = den * inv_wp1;
  Pv = cprop;
  Vv = cprop * gprop;
}

// Per-thread staging-task geometry (loop-invariant, precomputed once).
struct TaskGeo {
  int goff;      // within-plane element offset of the f2 load (clamped, even)
  int gc0;       // true global col of element 0 (may be OOB)
  float m0, m1;  // in-bounds masks for the 2 elements
  int wb;        // LDS byte offset (f4 {P0,V0,P1,V1} write)
};

__device__ __forceinline__ TaskGeo make_geo(int task, int h0, int w0) {
  TaskGeo G;
  const int R = task / 12;
  const int hq = task - R * 12;
  const int gh = h0 + R - 2;
  const int ghc = min(max(gh, 0), IMG_H - 1);
  const int g0 = w0 - 4 + 2 * hq;
  const int g0c = min(max(g0, 0), IMG_W - 2);     // even => 8B aligned
  G.goff = ghc * IMG_W + g0c;
  G.gc0 = g0;
  const bool rowv = (unsigned)gh < (unsigned)IMG_H;
  G.m0 = (rowv & ((unsigned)g0 < (unsigned)IMG_W)) ? 1.f : 0.f;
  G.m1 = (rowv & ((unsigned)(g0 + 1) < (unsigned)IMG_W)) ? 1.f : 0.f;
  G.wb = R * RSB + hq * 16;                       // 16B aligned
  return G;
}

// pointwise for 2 px + ONE interleaved ds_write_b128 {P0,V0,P1,V1}
__device__ __forceinline__ void stage_pv(f2 vd, f2 vc, f2 vg, f2 vx,
                                         const TaskGeo& G, float wpc,
                                         float inv_wp1, char* dst) {
  float P0, V0, P1, V1;
  pointwise_pv(vd[0], vc[0] * G.m0, vg[0], vx[0] * G.m0, G.gc0,
               wpc, inv_wp1, P0, V0);
  pointwise_pv(vd[1], vc[1] * G.m1, vg[1], vx[1] * G.m1, G.gc0 + 1,
               wpc, inv_wp1, P1, V1);
  f4 w; w[0] = P0; w[1] = V0; w[2] = P1; w[3] = V1;
  *(f4*)(dst + G.wb) = w;
}

// ---------------------------------------------------------------------------
// Fully fused kernel: pointwise prop + depthwise 5x5 + 1x1 channel conv.
//
// vs R5 (167us, phase-serialized, all pipes <45%):
//  1. Prefetch of the next channel pair is issued AFTER __syncthreads(), not
//     before: __syncthreads drains vmcnt(0), so a prefetch issued before the
//     barrier completes AT the barrier and hides nothing. Issued after, the
//     loads fly during conv+acc (~600+ cyc) and the next barrier's drain is
//     free.  (This was the structural bug in R5/R6.)
//  2. Two channels per barrier phase: 16 barriers instead of 32; 4 buffers
//     (pair-alternating; hazard: iter i+2's writes to pair q are separated
//     from iter i's conv reads of pair q by iter i+1's barrier in every
//     thread). Staging = 864 tasks / 512 thr (uniform; R5 left 80 idle).
//  3. P,V interleaved as f2 per pixel: staging = 1 ds_write_b128 per task
//     (was 2 b64), conv = 25 ds_read_b64 per channel (was 50 b32) — half the
//     LDS instruction count at identical bytes; lanes read consecutive 8B =
//     2-way aliasing = free (m136).
// LDS 27,648 B. Accumulators 64 VGPR statically indexed.
// ---------------------------------------------------------------------------
__global__ __launch_bounds__(NT, 4) void fused_kernel(
    const float* __restrict__ dp, const float* __restrict__ cdp,
    const float* __restrict__ gxp, const float* __restrict__ cgxp,
    const float* __restrict__ ws, const float* __restrict__ bias,
    float* __restrict__ out) {
  __shared__ __align__(16) char shb[4 * BUFB];  // 27,648 B

  const int t = threadIdx.x;

  // XCD-aware swizzle: 1024 blocks; image k -> XCD k (round-robin wg->XCD
  // assumption; wrong mapping is a harmless permutation).
  const int wg = blockIdx.x;
  const int virt = (wg & 7) * TILES + (wg >> 3);
  const int b = virt >> 7;                       // /128 tiles
  const int tile = virt & (TILES - 1);
  const int tx = tile & 15, ty = tile >> 4;      // 16 x 8 tile grid
  const int w0 = tx * TW, h0 = ty * TH;

  const float Ssw = ws[1856], Scw = ws[1857];
  const float epsS = EPSV * Ssw;
  const float oscale = rcpf_(Ssw) * rcpf_(Scw);

  // ---- staging task assignment (2 ch x 432 tasks = 864 over 512 thr) ----
  // round 0: t<432 -> (chA, task t); t>=432 -> (chB, task t-432)
  // round 1: t<352 -> (chB, task t+80)
  const int f0 = (t >= NTASK) ? 1 : 0;           // round-0 channel select
  const TaskGeo G0 = make_geo(t - NTASK * f0, h0, w0);
  const bool act1 = (t < 2 * NTASK - NT);        // t < 352
  const TaskGeo G1 = make_geo(min(t + (NT - NTASK), NTASK - 1), h0, w0);

  // ---- conv geometry ----
  const int x = t & (TW - 1);
  const int r = t >> 4;                          // 0..31
  const int cvb = r * RSB + (x + 2) * 8;         // window base byte
  const int pixoff = (h0 + r) * IMG_W + (w0 + x);

  const int planebase = b * NC * PLANE;

  float accN[32], accD[32];
  #pragma unroll
  for (int o = 0; o < 32; ++o) { accN[o] = 0.f; accD[o] = 0.f; }

  // prologue: prefetch channel pair {0,1}
  f2 d0, c0, g0v, x0, d1, c1, g1v, x1;
  {
    const int p0 = planebase + f0 * PLANE + G0.goff;
    d0 = *(const f2*)(dp + p0);  c0 = *(const f2*)(cdp + p0);
    g0v = *(const f2*)(gxp + p0); x0 = *(const f2*)(cgxp + p0);
    if (act1) {
      const int p1 = planebase + 1 * PLANE + G1.goff;
      d1 = *(const f2*)(dp + p1);  c1 = *(const f2*)(cdp + p1);
      g1v = *(const f2*)(gxp + p1); x1 = *(const f2*)(cgxp + p1);
    }
  }

  #pragma unroll 1
  for (int g = 0; g < NC; g += 2) {
    const int q = (g >> 1) & 1;                  // buffer pair select
    char* bufA = shb + (2 * q) * BUFB;           // channel g
    char* bufB = shb + (2 * q + 1) * BUFB;       // channel g+1

    const float wpA = ws[g], wpB = ws[g + 1];
    const float invA = rcpf_(wpA + 1.0f), invB = rcpf_(wpB + 1.0f);
    const float wp0 = f0 ? wpB : wpA;
    const float inv0 = f0 ? invB : invA;

    // stage both channels of this pair (regs prefetched last iteration)
    stage_pv(d0, c0, g0v, x0, G0, wp0, inv0, f0 ? bufB : bufA);
    if (act1) stage_pv(d1, c1, g1v, x1, G1, wpB, invB, bufB);

    __syncthreads();  // pair q complete (drains LDS writes + stale vmcnt)

    // prefetch next pair AFTER the barrier: loads fly during conv+acc and
    // the next barrier's vmcnt(0) drain costs nothing.
    if (g + 2 < NC) {
      const int p0 = planebase + (g + 2 + f0) * PLANE + G0.goff;
      d0 = *(const f2*)(dp + p0);  c0 = *(const f2*)(cdp + p0);
      g0v = *(const f2*)(gxp + p0); x0 = *(const f2*)(cgxp + p0);
      if (act1) {
        const int p1 = planebase + (g + 3) * PLANE + G1.goff;
        d1 = *(const f2*)(dp + p1);  c1 = *(const f2*)(cdp + p1);
        g1v = *(const f2*)(gxp + p1); x1 = *(const f2*)(cgxp + p1);
      }
    }

    // depthwise 5x5 for both channels at this thread's pixel
    // (25 ds_read_b64 per channel; interleaved {P,V} per tap)
    const char* bpA = bufA + cvb;
    const char* bpB = bufB + cvb;
    const float* swA = ws + 32 + g * 25;
    const float* swB = swA + 25;
    float DA = 0.f, NA = 0.f, DB = 0.f, NBv = 0.f;
    #pragma unroll
    for (int kr = 0; kr < 5; ++kr) {
      #pragma unroll
      for (int kc = 0; kc < 5; ++kc) {
        const int off = kr * RSB + kc * 8;
        const float wA = swA[kr * 5 + kc];
        const float wB = swB[kr * 5 + kc];
        const f2 pvA = *(const f2*)(bpA + off);
        const f2 pvB = *(const f2*)(bpB + off);
        DA  = fmaf(wA, pvA[0], DA);
        NA  = fmaf(wA, pvA[1], NA);
        DB  = fmaf(wB, pvB[0], DB);
        NBv = fmaf(wB, pvB[1], NBv);
      }
    }

    // rank-2 update of the 1x1-conv accumulators
    const float* cwA = ws + 832 + g * NO;
    const float* cwB = cwA + NO;
    #pragma unroll
    for (int o = 0; o < 32; ++o) {
      accD[o] = fmaf(cwB[o], DB, fmaf(cwA[o], DA, accD[o]));
      accN[o] = fmaf(cwB[o], NBv, fmaf(cwA[o], NA, accN[o]));
    }
    // next iteration stages the OTHER buffer pair; writes to THIS pair occur
    // two iterations later, fenced by the next iteration's barrier.
  }

  // epilogue: folded normalization + store (exact vs unfused version):
  //   gx[o]  = accN[o]/(accD[o] + EPS*Ssw) + bias[o]
  //   cgx[o] = accD[o]/(Ssw*Scw)
  const int ob = b * NO * PLANE + pixoff;
  #pragma unroll
  for (int o = 0; o < 32; ++o) {
    const float g = fmaf(accN[o], rcpf_(accD[o] + epsS), bias[o]);
    const float cg = accD[o] * oscale;
    out[ob + o * PLANE] = g;
    out[HALF + ob + o * PLANE] = cg;
  }
}

extern "C" void kernel_launch(void* const* d_in, const int* in_sizes, int n_in,
                              void* d_out, int out_size, void* d_ws, size_t ws_size,
                              hipStream_t stream) {
  const float* dp   = (const float*)d_in[0];
  const float* cdp  = (const float*)d_in[1];
  const float* gxp  = (const float*)d_in[2];
  const float* cgxp = (const float*)d_in[3];
  const float* wp   = (const float*)d_in[4];
  const float* sw   = (const float*)d_in[5];
  const float* cw   = (const float*)d_in[6];
  const float* bias = (const float*)d_in[7];
  float* out = (float*)d_out;
  float* ws  = (float*)d_ws;

  weights_kernel<<<1, 256, 0, stream>>>(wp, sw, cw, ws);
  fused_kernel<<<TILES * NB, NT, 0, stream>>>(dp, cdp, gxp, cgxp, ws, bias,
                                              out);
}